// Round 12
// baseline (118.997 us; speedup 1.0000x reference)
//
#include <hip/hip_runtime.h>

// ImplicitNetOC: u = clip(-pB) ; pB = relu(relu([x,t]W1+b1)W2+b2) @ (W3@Bmat) + b3@Bmat
// R24 = R23 (fp16 datapath, no lo-residual, 3 barriers/tile; measured 118.8 us,
// absmax 0.0039) with oc_main's barriers weakened from __syncthreads()
// (s_waitcnt vmcnt(0) lgkmcnt(0) + s_barrier) to LGKM-ONLY barriers
// (s_waitcnt lgkmcnt(0) + raw s_barrier):
//  - Correctness argument: cross-wave visibility at each barrier needs only
//    LDS writes drained (lgkmcnt). All global READS are read-only weights/x;
//    out STORES are per-wave-exclusive and never read back; every global->LDS
//    path is reg-staged, so the per-wave global->convert->ds_write dependency
//    is already enforced by the compiler's vmcnt-before-use. Dropping the
//    vmcnt drain cannot create a race -- it only lets A-frag prefetches and
//    out-stores stay in flight across barriers (T4, safest form; m201-template
//    idiom: asm waitcnt + __builtin_amdgcn_s_barrier). m139's null doesn't
//    apply: that needed vmcnt for global_load_lds visibility; we reg-stage.
//  - Everything else identical to R23 (math bit-identical).
// Readout: absmax must be exactly 0.00390625 (else revert); dur ~114-117 =
// win; <=1 us delta = compiler already hid the drains (accept/revert).

typedef _Float16 f16;
typedef _Float16 f16x8 __attribute__((ext_vector_type(8)));
typedef _Float16 f16x4 __attribute__((ext_vector_type(4)));
typedef float    f32x4 __attribute__((ext_vector_type(4)));

#define HID    256
#define SDIM   64
#define CDIM   16
#define BM     128
#define GRID   256      // 1024 tiles / ITERS
#define ITERS  4
// sH row: 256 f16 (512 B); sX row: 64 f16 (128 B); 16B granules XOR-swizzled.

// ws byte offsets (pack format unchanged from R8, dtype fp16)
#define OFF_W2P 0        // 8192 entries x 16 B (8kt x 16nt x 64lane)
#define OFF_W3P 131072   // 512 entries x 16 B (8kt x 64lane)
#define OFF_W1P 139264   // 2048 entries x 16 B (2kt x 16nt x 64lane)
#define OFF_B1E 172032   // 256 f32
#define OFF_B3B 173056   // 16 f32

#define MFMA(a, b, c) __builtin_amdgcn_mfma_f32_16x16x32_f16(a, b, c, 0, 0, 0)

// lgkm-only barrier: LDS writes drained, global loads/stores stay in flight.
#define BAR() do { asm volatile("s_waitcnt lgkmcnt(0)" ::: "memory"); \
                   __builtin_amdgcn_s_barrier(); } while (0)

// swizzled sH index: element (row=batch, h=hidden). granule = 8 f16 = 16 B.
__device__ __forceinline__ int sh_idx(int row, int h) {
  return (row << 8) + ((((h >> 3) ^ row) & 7) << 3) + (h & 7) + ((h >> 6) << 6);
}
// h < 256, granules/row = 32; swizzle only the low 3 granule bits:
// idx = row*256 + (g & ~7)*8 + ((g&7)^(row&7))*8 + (h&7), g = h>>3.

__device__ __forceinline__ int sx_idx(int row, int k) {
  return (row << 6) + ((((k >> 3) ^ row) & 7) << 3) + (k & 7);
}

// ---- pack kernel: W2/W1/W3B A-frags + folded biases -> ws. 22 x 512 ----
__global__ __launch_bounds__(512)
void oc_pack(const float* __restrict__ t,  const float* __restrict__ W1,
             const float* __restrict__ b1, const float* __restrict__ W2,
             const float* __restrict__ W3, const float* __restrict__ b3,
             const float* __restrict__ Bmat, char* __restrict__ ws) {
  const int gid = blockIdx.x * 512 + threadIdx.x;
  if (gid < 8192) {
    const int lane = gid & 63, tt = gid >> 6;
    const int nt = tt & 15, kt = tt >> 4;
    const int m = nt * 16 + (lane & 15);
    const int k0 = kt * 32 + ((lane >> 4) << 3);
    f16x8 v;
#pragma unroll
    for (int j = 0; j < 8; ++j) v[j] = (f16)W2[(k0 + j) * HID + m];
    *(f16x8*)((f16*)(ws + OFF_W2P) + (size_t)gid * 8) = v;
  } else if (gid < 8704) {
    const int e = gid - 8192, kt = e >> 6, fl = e & 63;
    const int r0 = kt * 32 + ((fl >> 4) << 3);
    const int c  = fl & 15;
    float aw[8];
#pragma unroll
    for (int j = 0; j < 8; ++j) aw[j] = 0.f;
    for (int m = 0; m < SDIM; ++m) {
      const float bm = Bmat[m * CDIM + c];
#pragma unroll
      for (int j = 0; j < 8; ++j) aw[j] = fmaf(W3[(r0 + j) * SDIM + m], bm, aw[j]);
    }
    f16x8 v;
#pragma unroll
    for (int j = 0; j < 8; ++j) v[j] = (f16)aw[j];
    *(f16x8*)((f16*)(ws + OFF_W3P) + (size_t)e * 8) = v;
  } else if (gid < 10752) {
    const int e = gid - 8704;
    const int lane = e & 63, tt = e >> 6;
    const int nt = tt & 15, kt = tt >> 4;
    const int m = nt * 16 + (lane & 15);
    const int k0 = kt * 32 + ((lane >> 4) << 3);
    f16x8 v;
#pragma unroll
    for (int j = 0; j < 8; ++j) v[j] = (f16)W1[(k0 + j) * HID + m];
    *(f16x8*)((f16*)(ws + OFF_W1P) + (size_t)e * 8) = v;
  } else if (gid < 11008) {
    const int h = gid - 10752;
    ((float*)(ws + OFF_B1E))[h] = b1[h] + t[0] * W1[SDIM * HID + h];  // fold t-col
  } else if (gid < 11024) {
    const int c = gid - 11008;
    float s = 0.f;
    for (int m = 0; m < SDIM; ++m) s = fmaf(b3[m], Bmat[m * CDIM + c], s);
    ((float*)(ws + OFF_B3B))[c] = s;
  }
}

// ---- main: 256 blocks x 512 threads (8 waves), 144 KB LDS, 1 block/CU ----
__global__ __launch_bounds__(512, 2)
void oc_main(const float* __restrict__ x, const float* __restrict__ b2,
             const char* __restrict__ ws, float* __restrict__ out) {
  __shared__ f16 sH1[BM * 256];   // H1 [batch][hidden] swizzled
  __shared__ f16 sH2[BM * 256];   // H2 (single fp16 -- no lo residual)
  __shared__ f16 sX [BM * 64];    // staged X [batch][k] swizzled
  const int tid  = threadIdx.x;
  const int wave = tid >> 6, lane = tid & 63;
  const int q    = lane >> 4, l = lane & 15;

  const f16* W2p = (const f16*)(ws + OFF_W2P);
  const f16* W3p = (const f16*)(ws + OFF_W3P);
  const f16* W1p = (const f16*)(ws + OFF_W1P);

  // ---- initial X stage: 2048 float4, 4 per thread ----
  {
    const float* xp = x + (size_t)blockIdx.x * BM * SDIM;
#pragma unroll
    for (int i = 0; i < 4; ++i) {
      const int e = i * 512 + tid;           // 2048 float4 = 128 x 64 floats
      const int r = e >> 4, k4 = (e & 15) * 4;
      const float4 v = *(const float4*)(xp + r * SDIM + k4);
      f16x4 w = {(f16)v.x, (f16)v.y, (f16)v.z, (f16)v.w};
      *(f16x4*)(&sX[sx_idx(r, k4)]) = w;
    }
  }

  // ---- biases: wave owns 32 hidden (mt 0..1), h0 = 32*wave + 16*mt + 4*q ----
  f32x4 b1e[2], b2e[2];
#pragma unroll
  for (int mt = 0; mt < 2; ++mt) {
    const int h0 = 32 * wave + 16 * mt + 4 * q;
    const float4 v1 = *(const float4*)((const float*)(ws + OFF_B1E) + h0);
    const float4 v2 = *(const float4*)(b2 + h0);
    b1e[mt] = (f32x4){v1.x, v1.y, v1.z, v1.w};
    b2e[mt] = (f32x4){v2.x, v2.y, v2.z, v2.w};
  }
  f32x4 b3t;
  {
    const float4 v = *(const float4*)((const float*)(ws + OFF_B3B) + 4 * q);
    b3t = (f32x4){v.x, v.y, v.z, v.w};
  }
  BAR();   // sX staged (lgkm-only; bias loads drain at their use)

  f32x4 acc[2][8];   // [mt][nt]

  for (int it = 0; it < ITERS; ++it) {
    const int tile = blockIdx.x + it * GRID;

    // ---- P0 / layer 1: H1 = relu(W1^T X^T + b1); M=32/wave, N=128 batch ----
#pragma unroll
    for (int mt = 0; mt < 2; ++mt)
#pragma unroll
      for (int nt = 0; nt < 8; ++nt) acc[mt][nt] = b1e[mt];
#pragma unroll
    for (int kt = 0; kt < 2; ++kt) {
      const f16x8 w1a = *(const f16x8*)(W1p + ((size_t)(kt * 16 + 2 * wave    ) * 64 + lane) * 8);
      const f16x8 w1b = *(const f16x8*)(W1p + ((size_t)(kt * 16 + 2 * wave + 1) * 64 + lane) * 8);
#pragma unroll
      for (int nt = 0; nt < 8; ++nt) {
        const f16x8 b = *(const f16x8*)(&sX[sx_idx(16 * nt + l, 32 * kt + 8 * q)]);
        acc[0][nt] = MFMA(w1a, b, acc[0][nt]);
        acc[1][nt] = MFMA(w1b, b, acc[1][nt]);
      }
    }
#pragma unroll
    for (int mt = 0; mt < 2; ++mt) {
      const int h0 = 32 * wave + 16 * mt + 4 * q;
#pragma unroll
      for (int nt = 0; nt < 8; ++nt) {
        f16x4 v;
#pragma unroll
        for (int r = 0; r < 4; ++r) v[r] = (f16)fmaxf(acc[mt][nt][r], 0.f);
        *(f16x4*)(&sH1[sh_idx(16 * nt + l, h0)]) = v;
      }
    }
    BAR();   // A: H1 visible; sX reads done (W2 prefetches may stay in flight)

    // ---- P1 / layer 2: H2 = relu(W2^T H1 + b2), K=256; then writeback ----
#pragma unroll
    for (int mt = 0; mt < 2; ++mt)
#pragma unroll
      for (int nt = 0; nt < 8; ++nt) acc[mt][nt] = b2e[mt];
#pragma unroll
    for (int kt = 0; kt < 8; ++kt) {
      const f16x8 w2a = *(const f16x8*)(W2p + ((size_t)(kt * 16 + 2 * wave    ) * 64 + lane) * 8);
      const f16x8 w2b = *(const f16x8*)(W2p + ((size_t)(kt * 16 + 2 * wave + 1) * 64 + lane) * 8);
#pragma unroll
      for (int nt = 0; nt < 8; ++nt) {
        const f16x8 b = *(const f16x8*)(&sH1[sh_idx(16 * nt + l, 32 * kt + 8 * q)]);
        acc[0][nt] = MFMA(w2a, b, acc[0][nt]);
        acc[1][nt] = MFMA(w2b, b, acc[1][nt]);
      }
    }
    // H2 writeback: single fp16 store to sH2 (sH1 untouched)
#pragma unroll
    for (int mt = 0; mt < 2; ++mt) {
      const int h0 = 32 * wave + 16 * mt + 4 * q;
#pragma unroll
      for (int nt = 0; nt < 8; ++nt) {
        f16x4 hi;
#pragma unroll
        for (int r = 0; r < 4; ++r) hi[r] = (f16)fmaxf(acc[mt][nt][r], 0.f);
        *(f16x4*)(&sH2[sh_idx(16 * nt + l, h0)]) = hi;
      }
    }
    BAR();   // C: H2 visible

    // ---- P2: layer 3 (waves 0-3) || stage next X (waves 4-7) ----
    if (wave < 4) {
#pragma unroll
      for (int g = 0; g < 2; ++g) {
        const int row = 32 * wave + 16 * g + l;
        f32x4 a3 = b3t;
#pragma unroll
        for (int kt = 0; kt < 8; ++kt) {
          const f16x8 w3 = *(const f16x8*)(W3p + ((size_t)kt * 64 + lane) * 8);
          const f16x8 bh = *(const f16x8*)(&sH2[sh_idx(row, 32 * kt + 8 * q)]);
          a3 = MFMA(w3, bh, a3);
        }
        f32x4 o;
#pragma unroll
        for (int r = 0; r < 4; ++r)
          o[r] = fminf(fmaxf(-a3[r], -1.f), 1.f);
        *(float4*)(&out[((size_t)tile * BM + row) * CDIM + 4 * q]) = *(float4*)&o;
      }
    } else if (it + 1 < ITERS) {
      const float* xp = x + (size_t)(tile + GRID) * BM * SDIM;
      const int tid2 = tid - 256;            // 0..255
#pragma unroll
      for (int i = 0; i < 8; ++i) {
        const int e = i * 256 + tid2;        // 2048 float4 = 128 x 64 floats
        const int r = e >> 4, k4 = (e & 15) * 4;
        const float4 v = *(const float4*)(xp + r * SDIM + k4);
        f16x4 w = {(f16)v.x, (f16)v.y, (f16)v.z, (f16)v.w};
        *(f16x4*)(&sX[sx_idx(r, k4)]) = w;
      }
    }
    BAR();   // D: L3 sH2 reads + sX stage done (out-stores stay in flight)
  }
}

extern "C" void kernel_launch(void* const* d_in, const int* in_sizes, int n_in,
                              void* d_out, int out_size, void* d_ws, size_t ws_size,
                              hipStream_t stream) {
  const float* x    = (const float*)d_in[0];
  const float* t    = (const float*)d_in[1];
  const float* W1   = (const float*)d_in[2];
  const float* b1   = (const float*)d_in[3];
  const float* W2   = (const float*)d_in[4];
  const float* b2   = (const float*)d_in[5];
  const float* W3   = (const float*)d_in[6];
  const float* b3   = (const float*)d_in[7];
  const float* Bmat = (const float*)d_in[8];
  float* out = (float*)d_out;
  char*  ws  = (char*)d_ws;

  hipLaunchKernelGGL(oc_pack, dim3(22), dim3(512), 0, stream,
                     t, W1, b1, W2, W3, b3, Bmat, ws);
  hipLaunchKernelGGL(oc_main, dim3(GRID), dim3(512), 0, stream,
                     x, b2, ws, out);
}

// Round 13
// 117.902 us; speedup vs baseline: 1.0093x; 1.0093x over previous
//
#include <hip/hip_runtime.h>

// ImplicitNetOC: u = clip(-pB) ; pB = relu(relu([x,t]W1+b1)W2+b2) @ (W3@Bmat) + b3@Bmat
// R25 = FINAL: R23 verbatim (session best, measured 118.8 us / absmax 0.0039).
// R24's lgkm-only barriers were neutral (119.0, within noise) -> reverted to
// plain __syncthreads per the simplicity rule.
//
// Session summary (R13-R24):
//  - 125.9 -> 118.8 us. Wins: GRID=256/ITERS=4 reshape (-2.4); fp16 datapath +
//    lo-residual elimination + barrier B removal (-3.2, absmax 4x better:
//    error floor was bf16 quantization, not scheduling).
//  - Falsified levers (each with counter evidence):
//    * acc[4][4] retile: arch-VGPR budget is 128 for this family REGARDLESS
//      of __launch_bounds__ arg2 -> ~84 MB spill (R14/R15/R18); rolled kt
//      avoids spill but is latency-bound at 2 waves/SIMD (R17, 45.3 us).
//    * Occupancy: BM=64 2-blk/CU blocked by regs (R19); 16-wave 1024-thr
//      block doubled Occupancy 17.8->37.8% with ZERO time delta (R20) ->
//      phase floors are shared LDS-pipe + barrier lockstep, not TLP.
//    * vmcnt-drain removal at barriers: neutral (R24) -> already hidden.
//  - dur decomposition: ~88 us harness ws-poison fills (2x268 MB @ 75-78%
//    HBM peak -- their own roofline, untouchable) + ~1.5 us pack + ~30 us
//    oc_main (vs ~11-15 us LDS/MFMA floor).
//  - Documented next step for a future session: disasm-first (-save-temps
//    mnemonic histogram of the P1 loop), then cross-tile deep pipeline
//    (dbuf sH1) only if the histogram shows issue-side stall, not pipe-bound.
// Structure: 512 thr / 8 waves, BM=128, GRID=256, ITERS=4, acc[2][8]
// (M=32 x N=128 per wave), fp16 MFMA 16x16x32, 144 KB LDS, XOR granule
// swizzle, 3 barriers/tile (A: sH1 ready; C: sH2 ready; D: L3+stage done).

typedef _Float16 f16;
typedef _Float16 f16x8 __attribute__((ext_vector_type(8)));
typedef _Float16 f16x4 __attribute__((ext_vector_type(4)));
typedef float    f32x4 __attribute__((ext_vector_type(4)));

#define HID    256
#define SDIM   64
#define CDIM   16
#define BM     128
#define GRID   256      // 1024 tiles / ITERS
#define ITERS  4
// sH row: 256 f16 (512 B); sX row: 64 f16 (128 B); 16B granules XOR-swizzled.

// ws byte offsets (pack format unchanged from R8, dtype fp16)
#define OFF_W2P 0        // 8192 entries x 16 B (8kt x 16nt x 64lane)
#define OFF_W3P 131072   // 512 entries x 16 B (8kt x 64lane)
#define OFF_W1P 139264   // 2048 entries x 16 B (2kt x 16nt x 64lane)
#define OFF_B1E 172032   // 256 f32
#define OFF_B3B 173056   // 16 f32

#define MFMA(a, b, c) __builtin_amdgcn_mfma_f32_16x16x32_f16(a, b, c, 0, 0, 0)

// swizzled sH index: element (row=batch, h=hidden). granule = 8 f16 = 16 B.
__device__ __forceinline__ int sh_idx(int row, int h) {
  return (row << 8) + ((((h >> 3) ^ row) & 7) << 3) + (h & 7) + ((h >> 6) << 6);
}
// h < 256, granules/row = 32; swizzle only the low 3 granule bits:
// idx = row*256 + (g & ~7)*8 + ((g&7)^(row&7))*8 + (h&7), g = h>>3.

__device__ __forceinline__ int sx_idx(int row, int k) {
  return (row << 6) + ((((k >> 3) ^ row) & 7) << 3) + (k & 7);
}

// ---- pack kernel: W2/W1/W3B A-frags + folded biases -> ws. 22 x 512 ----
__global__ __launch_bounds__(512)
void oc_pack(const float* __restrict__ t,  const float* __restrict__ W1,
             const float* __restrict__ b1, const float* __restrict__ W2,
             const float* __restrict__ W3, const float* __restrict__ b3,
             const float* __restrict__ Bmat, char* __restrict__ ws) {
  const int gid = blockIdx.x * 512 + threadIdx.x;
  if (gid < 8192) {
    const int lane = gid & 63, tt = gid >> 6;
    const int nt = tt & 15, kt = tt >> 4;
    const int m = nt * 16 + (lane & 15);
    const int k0 = kt * 32 + ((lane >> 4) << 3);
    f16x8 v;
#pragma unroll
    for (int j = 0; j < 8; ++j) v[j] = (f16)W2[(k0 + j) * HID + m];
    *(f16x8*)((f16*)(ws + OFF_W2P) + (size_t)gid * 8) = v;
  } else if (gid < 8704) {
    const int e = gid - 8192, kt = e >> 6, fl = e & 63;
    const int r0 = kt * 32 + ((fl >> 4) << 3);
    const int c  = fl & 15;
    float aw[8];
#pragma unroll
    for (int j = 0; j < 8; ++j) aw[j] = 0.f;
    for (int m = 0; m < SDIM; ++m) {
      const float bm = Bmat[m * CDIM + c];
#pragma unroll
      for (int j = 0; j < 8; ++j) aw[j] = fmaf(W3[(r0 + j) * SDIM + m], bm, aw[j]);
    }
    f16x8 v;
#pragma unroll
    for (int j = 0; j < 8; ++j) v[j] = (f16)aw[j];
    *(f16x8*)((f16*)(ws + OFF_W3P) + (size_t)e * 8) = v;
  } else if (gid < 10752) {
    const int e = gid - 8704;
    const int lane = e & 63, tt = e >> 6;
    const int nt = tt & 15, kt = tt >> 4;
    const int m = nt * 16 + (lane & 15);
    const int k0 = kt * 32 + ((lane >> 4) << 3);
    f16x8 v;
#pragma unroll
    for (int j = 0; j < 8; ++j) v[j] = (f16)W1[(k0 + j) * HID + m];
    *(f16x8*)((f16*)(ws + OFF_W1P) + (size_t)e * 8) = v;
  } else if (gid < 11008) {
    const int h = gid - 10752;
    ((float*)(ws + OFF_B1E))[h] = b1[h] + t[0] * W1[SDIM * HID + h];  // fold t-col
  } else if (gid < 11024) {
    const int c = gid - 11008;
    float s = 0.f;
    for (int m = 0; m < SDIM; ++m) s = fmaf(b3[m], Bmat[m * CDIM + c], s);
    ((float*)(ws + OFF_B3B))[c] = s;
  }
}

// ---- main: 256 blocks x 512 threads (8 waves), 144 KB LDS, 1 block/CU ----
__global__ __launch_bounds__(512, 2)
void oc_main(const float* __restrict__ x, const float* __restrict__ b2,
             const char* __restrict__ ws, float* __restrict__ out) {
  __shared__ f16 sH1[BM * 256];   // H1 [batch][hidden] swizzled
  __shared__ f16 sH2[BM * 256];   // H2 (single fp16 -- no lo residual)
  __shared__ f16 sX [BM * 64];    // staged X [batch][k] swizzled
  const int tid  = threadIdx.x;
  const int wave = tid >> 6, lane = tid & 63;
  const int q    = lane >> 4, l = lane & 15;

  const f16* W2p = (const f16*)(ws + OFF_W2P);
  const f16* W3p = (const f16*)(ws + OFF_W3P);
  const f16* W1p = (const f16*)(ws + OFF_W1P);

  // ---- initial X stage: 2048 float4, 4 per thread ----
  {
    const float* xp = x + (size_t)blockIdx.x * BM * SDIM;
#pragma unroll
    for (int i = 0; i < 4; ++i) {
      const int e = i * 512 + tid;           // 2048 float4 = 128 x 64 floats
      const int r = e >> 4, k4 = (e & 15) * 4;
      const float4 v = *(const float4*)(xp + r * SDIM + k4);
      f16x4 w = {(f16)v.x, (f16)v.y, (f16)v.z, (f16)v.w};
      *(f16x4*)(&sX[sx_idx(r, k4)]) = w;
    }
  }

  // ---- biases: wave owns 32 hidden (mt 0..1), h0 = 32*wave + 16*mt + 4*q ----
  f32x4 b1e[2], b2e[2];
#pragma unroll
  for (int mt = 0; mt < 2; ++mt) {
    const int h0 = 32 * wave + 16 * mt + 4 * q;
    const float4 v1 = *(const float4*)((const float*)(ws + OFF_B1E) + h0);
    const float4 v2 = *(const float4*)(b2 + h0);
    b1e[mt] = (f32x4){v1.x, v1.y, v1.z, v1.w};
    b2e[mt] = (f32x4){v2.x, v2.y, v2.z, v2.w};
  }
  f32x4 b3t;
  {
    const float4 v = *(const float4*)((const float*)(ws + OFF_B3B) + 4 * q);
    b3t = (f32x4){v.x, v.y, v.z, v.w};
  }
  __syncthreads();   // sX staged

  f32x4 acc[2][8];   // [mt][nt]

  for (int it = 0; it < ITERS; ++it) {
    const int tile = blockIdx.x + it * GRID;

    // ---- P0 / layer 1: H1 = relu(W1^T X^T + b1); M=32/wave, N=128 batch ----
#pragma unroll
    for (int mt = 0; mt < 2; ++mt)
#pragma unroll
      for (int nt = 0; nt < 8; ++nt) acc[mt][nt] = b1e[mt];
#pragma unroll
    for (int kt = 0; kt < 2; ++kt) {
      const f16x8 w1a = *(const f16x8*)(W1p + ((size_t)(kt * 16 + 2 * wave    ) * 64 + lane) * 8);
      const f16x8 w1b = *(const f16x8*)(W1p + ((size_t)(kt * 16 + 2 * wave + 1) * 64 + lane) * 8);
#pragma unroll
      for (int nt = 0; nt < 8; ++nt) {
        const f16x8 b = *(const f16x8*)(&sX[sx_idx(16 * nt + l, 32 * kt + 8 * q)]);
        acc[0][nt] = MFMA(w1a, b, acc[0][nt]);
        acc[1][nt] = MFMA(w1b, b, acc[1][nt]);
      }
    }
#pragma unroll
    for (int mt = 0; mt < 2; ++mt) {
      const int h0 = 32 * wave + 16 * mt + 4 * q;
#pragma unroll
      for (int nt = 0; nt < 8; ++nt) {
        f16x4 v;
#pragma unroll
        for (int r = 0; r < 4; ++r) v[r] = (f16)fmaxf(acc[mt][nt][r], 0.f);
        *(f16x4*)(&sH1[sh_idx(16 * nt + l, h0)]) = v;
      }
    }
    __syncthreads();   // A: H1 visible; sX reads done

    // ---- P1 / layer 2: H2 = relu(W2^T H1 + b2), K=256; then writeback ----
#pragma unroll
    for (int mt = 0; mt < 2; ++mt)
#pragma unroll
      for (int nt = 0; nt < 8; ++nt) acc[mt][nt] = b2e[mt];
#pragma unroll
    for (int kt = 0; kt < 8; ++kt) {
      const f16x8 w2a = *(const f16x8*)(W2p + ((size_t)(kt * 16 + 2 * wave    ) * 64 + lane) * 8);
      const f16x8 w2b = *(const f16x8*)(W2p + ((size_t)(kt * 16 + 2 * wave + 1) * 64 + lane) * 8);
#pragma unroll
      for (int nt = 0; nt < 8; ++nt) {
        const f16x8 b = *(const f16x8*)(&sH1[sh_idx(16 * nt + l, 32 * kt + 8 * q)]);
        acc[0][nt] = MFMA(w2a, b, acc[0][nt]);
        acc[1][nt] = MFMA(w2b, b, acc[1][nt]);
      }
    }
    // H2 writeback: single fp16 store to sH2 (sH1 untouched -> no barrier B)
#pragma unroll
    for (int mt = 0; mt < 2; ++mt) {
      const int h0 = 32 * wave + 16 * mt + 4 * q;
#pragma unroll
      for (int nt = 0; nt < 8; ++nt) {
        f16x4 hi;
#pragma unroll
        for (int r = 0; r < 4; ++r) hi[r] = (f16)fmaxf(acc[mt][nt][r], 0.f);
        *(f16x4*)(&sH2[sh_idx(16 * nt + l, h0)]) = hi;
      }
    }
    __syncthreads();   // C: H2 visible

    // ---- P2: layer 3 (waves 0-3) || stage next X (waves 4-7) ----
    if (wave < 4) {
#pragma unroll
      for (int g = 0; g < 2; ++g) {
        const int row = 32 * wave + 16 * g + l;
        f32x4 a3 = b3t;
#pragma unroll
        for (int kt = 0; kt < 8; ++kt) {
          const f16x8 w3 = *(const f16x8*)(W3p + ((size_t)kt * 64 + lane) * 8);
          const f16x8 bh = *(const f16x8*)(&sH2[sh_idx(row, 32 * kt + 8 * q)]);
          a3 = MFMA(w3, bh, a3);
        }
        f32x4 o;
#pragma unroll
        for (int r = 0; r < 4; ++r)
          o[r] = fminf(fmaxf(-a3[r], -1.f), 1.f);
        *(float4*)(&out[((size_t)tile * BM + row) * CDIM + 4 * q]) = *(float4*)&o;
      }
    } else if (it + 1 < ITERS) {
      const float* xp = x + (size_t)(tile + GRID) * BM * SDIM;
      const int tid2 = tid - 256;            // 0..255
#pragma unroll
      for (int i = 0; i < 8; ++i) {
        const int e = i * 256 + tid2;        // 2048 float4 = 128 x 64 floats
        const int r = e >> 4, k4 = (e & 15) * 4;
        const float4 v = *(const float4*)(xp + r * SDIM + k4);
        f16x4 w = {(f16)v.x, (f16)v.y, (f16)v.z, (f16)v.w};
        *(f16x4*)(&sX[sx_idx(r, k4)]) = w;
      }
    }
    __syncthreads();   // D: L3 sH2 reads + sX stage done before next tile
  }
}

extern "C" void kernel_launch(void* const* d_in, const int* in_sizes, int n_in,
                              void* d_out, int out_size, void* d_ws, size_t ws_size,
                              hipStream_t stream) {
  const float* x    = (const float*)d_in[0];
  const float* t    = (const float*)d_in[1];
  const float* W1   = (const float*)d_in[2];
  const float* b1   = (const float*)d_in[3];
  const float* W2   = (const float*)d_in[4];
  const float* b2   = (const float*)d_in[5];
  const float* W3   = (const float*)d_in[6];
  const float* b3   = (const float*)d_in[7];
  const float* Bmat = (const float*)d_in[8];
  float* out = (float*)d_out;
  char*  ws  = (char*)d_ws;

  hipLaunchKernelGGL(oc_pack, dim3(22), dim3(512), 0, stream,
                     t, W1, b1, W2, W3, b3, Bmat, ws);
  hipLaunchKernelGGL(oc_main, dim3(GRID), dim3(512), 0, stream,
                     x, b2, ws, out);
}